// Round 1
// baseline (5818.043 us; speedup 1.0000x reference)
//
#include <hip/hip_runtime.h>
#include <math.h>

#define N_ 4
#define T_ 2048
#define C_ 1024
#define H_ 16
#define D_ 64
#define NTC (N_*T_*C_)   // 8388608 elements per buffer

// ---------------------------------------------------------------------------
// Kernel 1: Y = X @ W^T for W in {Wq, Wk, Wv}; output written in [N*H, T, D]
// layout so attention reads are contiguous per head.
// X: [8192, 1024] row-major. W: [1024, 1024] row-major (y[j] = sum_c x[c]*W[j][c]).
// ---------------------------------------------------------------------------
__global__ __launch_bounds__(256) void qkv_gemm(const float* __restrict__ X,
                                                const float* __restrict__ Wq,
                                                const float* __restrict__ Wk,
                                                const float* __restrict__ Wv,
                                                float* __restrict__ ws) {
    const int z = blockIdx.z;
    const float* __restrict__ W = (z == 0) ? Wq : ((z == 1) ? Wk : Wv);
    float* __restrict__ Y = ws + (size_t)z * NTC;

    __shared__ float As[64][17];   // [row][k]  pad 17 to break bank conflicts
    __shared__ float Bs[16][65];   // [k][col]

    const int tid = threadIdx.x;
    const int tx = tid & 15;        // col group 0..15
    const int ty = tid >> 4;        // row group 0..15
    const int rowBase = blockIdx.x * 64;
    const int colBase = blockIdx.y * 64;

    float acc[4][4] = {};

    for (int k0 = 0; k0 < C_; k0 += 16) {
        // Load A tile: 64 rows x 16 k — 4 floats per thread
        {
            const int r = tid >> 2;           // 0..63
            const int c = (tid & 3) * 4;      // 0,4,8,12
            const float4 v = *(const float4*)&X[(size_t)(rowBase + r) * C_ + k0 + c];
            As[r][c + 0] = v.x; As[r][c + 1] = v.y; As[r][c + 2] = v.z; As[r][c + 3] = v.w;
        }
        // Load B tile: Bs[kc][j] = W[colBase+j][k0+kc]
        {
            const int j = tid >> 2;           // 0..63 (output col / W row)
            const int c = (tid & 3) * 4;      // k chunk
            const float4 v = *(const float4*)&W[(size_t)(colBase + j) * C_ + k0 + c];
            Bs[c + 0][j] = v.x; Bs[c + 1][j] = v.y; Bs[c + 2][j] = v.z; Bs[c + 3][j] = v.w;
        }
        __syncthreads();
        #pragma unroll
        for (int kk = 0; kk < 16; ++kk) {
            float a[4], b[4];
            #pragma unroll
            for (int i = 0; i < 4; ++i) a[i] = As[ty * 4 + i][kk];
            #pragma unroll
            for (int j = 0; j < 4; ++j) b[j] = Bs[kk][tx * 4 + j];
            #pragma unroll
            for (int i = 0; i < 4; ++i)
                #pragma unroll
                for (int j = 0; j < 4; ++j)
                    acc[i][j] = fmaf(a[i], b[j], acc[i][j]);
        }
        __syncthreads();
    }

    // Write out in [N*H, T, D] layout: Y[((n*H+h)*T + t)*D + d]
    #pragma unroll
    for (int i = 0; i < 4; ++i) {
        const int r = rowBase + ty * 4 + i;
        const int n = r >> 11, t = r & (T_ - 1);
        #pragma unroll
        for (int j = 0; j < 4; ++j) {
            const int cc = colBase + tx * 4 + j;
            const int h = cc >> 6, d = cc & 63;
            Y[((size_t)((n * H_ + h) * T_ + t)) * D_ + d] = acc[i][j];
        }
    }
}

// ---------------------------------------------------------------------------
// Kernel 2: causal flash attention, one thread per (head, query row).
// q/k/v in [NH=64, T=2048, D=64]; scale = 1/sqrt(C) = 1/32.
// ---------------------------------------------------------------------------
__global__ __launch_bounds__(256) void attn_kernel(const float* __restrict__ qb,
                                                   const float* __restrict__ kb,
                                                   const float* __restrict__ vb,
                                                   float* __restrict__ ob) {
    const int g = blockIdx.x * 256 + threadIdx.x;   // 0 .. N*H*T-1
    const int nh = g >> 11;                          // / T
    const int t  = g & (T_ - 1);
    const size_t base = (size_t)nh * T_ * D_;

    const float4* __restrict__ qp = (const float4*)(qb + base + (size_t)t * D_);
    const float4* __restrict__ kp = (const float4*)(kb + base);
    const float4* __restrict__ vp = (const float4*)(vb + base);

    float4 q4[16];
    #pragma unroll
    for (int i = 0; i < 16; ++i) q4[i] = qp[i];

    float m = -INFINITY, l = 0.f;
    float4 acc[16];
    #pragma unroll
    for (int i = 0; i < 16; ++i) acc[i] = make_float4(0.f, 0.f, 0.f, 0.f);

    for (int kidx = 0; kidx <= t; ++kidx) {
        const float4* krow = kp + kidx * 16;
        float s = 0.f;
        #pragma unroll
        for (int i = 0; i < 16; ++i) {
            const float4 kv = krow[i];
            s += q4[i].x * kv.x + q4[i].y * kv.y + q4[i].z * kv.z + q4[i].w * kv.w;
        }
        s *= 0.03125f;   // 1/sqrt(1024)

        float p;
        if (s > m) {                       // new running max (rare after warmup)
            const float f = __expf(m - s); // exp(-inf)=0 handles first iteration
            l *= f;
            #pragma unroll
            for (int i = 0; i < 16; ++i) {
                acc[i].x *= f; acc[i].y *= f; acc[i].z *= f; acc[i].w *= f;
            }
            m = s;
            p = 1.f;
        } else {
            p = __expf(s - m);
        }
        l += p;

        const float4* vrow = vp + kidx * 16;
        #pragma unroll
        for (int i = 0; i < 16; ++i) {
            const float4 vv = vrow[i];
            acc[i].x = fmaf(p, vv.x, acc[i].x);
            acc[i].y = fmaf(p, vv.y, acc[i].y);
            acc[i].z = fmaf(p, vv.z, acc[i].z);
            acc[i].w = fmaf(p, vv.w, acc[i].w);
        }
    }

    const float inv = 1.f / l;
    float4* op = (float4*)(ob + base + (size_t)t * D_);
    #pragma unroll
    for (int i = 0; i < 16; ++i) {
        op[i] = make_float4(acc[i].x * inv, acc[i].y * inv, acc[i].z * inv, acc[i].w * inv);
    }
}

// ---------------------------------------------------------------------------
// Kernel 3: out = attn_out @ Wo^T + bo. attn_out is in [N*H, T, D] layout;
// logical A[r][c] with r=n*T+t, c=h*D+d lives at ((n*H+h)*T+t)*D+d.
// ---------------------------------------------------------------------------
__global__ __launch_bounds__(256) void out_gemm(const float* __restrict__ A,
                                                const float* __restrict__ Wo,
                                                const float* __restrict__ bo,
                                                float* __restrict__ out) {
    __shared__ float As[64][17];
    __shared__ float Bs[16][65];

    const int tid = threadIdx.x;
    const int tx = tid & 15;
    const int ty = tid >> 4;
    const int rowBase = blockIdx.x * 64;
    const int colBase = blockIdx.y * 64;

    float acc[4][4] = {};

    for (int k0 = 0; k0 < C_; k0 += 16) {
        {
            const int r = rowBase + (tid >> 2);
            const int c = k0 + (tid & 3) * 4;
            const int n = r >> 11, t = r & (T_ - 1);
            const int h = c >> 6, d = c & 63;
            const float4 v = *(const float4*)&A[((size_t)((n * H_ + h) * T_ + t)) * D_ + d];
            const int rr = tid >> 2, cc = (tid & 3) * 4;
            As[rr][cc + 0] = v.x; As[rr][cc + 1] = v.y; As[rr][cc + 2] = v.z; As[rr][cc + 3] = v.w;
        }
        {
            const int j = tid >> 2;
            const int c = (tid & 3) * 4;
            const float4 v = *(const float4*)&Wo[(size_t)(colBase + j) * C_ + k0 + c];
            Bs[c + 0][j] = v.x; Bs[c + 1][j] = v.y; Bs[c + 2][j] = v.z; Bs[c + 3][j] = v.w;
        }
        __syncthreads();
        #pragma unroll
        for (int kk = 0; kk < 16; ++kk) {
            float a[4], b[4];
            #pragma unroll
            for (int i = 0; i < 4; ++i) a[i] = As[ty * 4 + i][kk];
            #pragma unroll
            for (int j = 0; j < 4; ++j) b[j] = Bs[kk][tx * 4 + j];
            #pragma unroll
            for (int i = 0; i < 4; ++i)
                #pragma unroll
                for (int j = 0; j < 4; ++j)
                    acc[i][j] = fmaf(a[i], b[j], acc[i][j]);
        }
        __syncthreads();
    }

    #pragma unroll
    for (int i = 0; i < 4; ++i) {
        const int r = rowBase + ty * 4 + i;
        #pragma unroll
        for (int j = 0; j < 4; ++j) {
            const int cc = colBase + tx * 4 + j;
            out[(size_t)r * C_ + cc] = acc[i][j] + bo[cc];
        }
    }
}

// ---------------------------------------------------------------------------
extern "C" void kernel_launch(void* const* d_in, const int* in_sizes, int n_in,
                              void* d_out, int out_size, void* d_ws, size_t ws_size,
                              hipStream_t stream) {
    const float* x  = (const float*)d_in[0];
    const float* Wq = (const float*)d_in[1];
    const float* Wk = (const float*)d_in[2];
    const float* Wv = (const float*)d_in[3];
    const float* Wo = (const float*)d_in[4];
    const float* bo = (const float*)d_in[5];
    float* out = (float*)d_out;
    float* ws  = (float*)d_ws;   // needs 4*NTC*4B = 134.2 MB

    float* q_buf = ws;
    float* k_buf = ws + (size_t)NTC;
    float* v_buf = ws + (size_t)2 * NTC;
    float* a_buf = ws + (size_t)3 * NTC;

    // QKV projections: M=8192 rows, N=1024 cols, 64x64 tiles, z = {q,k,v}
    dim3 g1(N_ * T_ / 64, C_ / 64, 3);
    qkv_gemm<<<g1, 256, 0, stream>>>(x, Wq, Wk, Wv, ws);

    // Attention: one thread per (head, query row)
    attn_kernel<<<(N_ * H_ * T_) / 256, 256, 0, stream>>>(q_buf, k_buf, v_buf, a_buf);

    // Output projection + bias
    dim3 g3(N_ * T_ / 64, C_ / 64);
    out_gemm<<<g3, 256, 0, stream>>>(a_buf, Wo, bo, out);
}

// Round 2
// 1625.363 us; speedup vs baseline: 3.5795x; 3.5795x over previous
//
#include <hip/hip_runtime.h>
#include <math.h>

#define N_ 4
#define T_ 2048
#define C_ 1024
#define H_ 16
#define D_ 64
#define NTC (N_*T_*C_)   // 8388608 elements per buffer

typedef float f32x4 __attribute__((ext_vector_type(4)));
typedef short bf16x8 __attribute__((ext_vector_type(8)));   // 8 bf16 payloads (4 VGPRs)

static __device__ __forceinline__ unsigned short f2bf(float f) {
    union { float f; unsigned u; } v; v.f = f;
    unsigned r = v.u + 0x7FFFu + ((v.u >> 16) & 1u);   // RNE
    return (unsigned short)(r >> 16);
}

// ---------------------------------------------------------------------------
// Kernel 1: Y = X @ W^T for W in {Wq, Wk, Wv}; bf16 output in [N*H, T, D].
// ---------------------------------------------------------------------------
__global__ __launch_bounds__(256) void qkv_gemm(const float* __restrict__ X,
                                                const float* __restrict__ Wq,
                                                const float* __restrict__ Wk,
                                                const float* __restrict__ Wv,
                                                unsigned short* __restrict__ ws) {
    const int z = blockIdx.z;
    const float* __restrict__ W = (z == 0) ? Wq : ((z == 1) ? Wk : Wv);
    unsigned short* __restrict__ Y = ws + (size_t)z * NTC;

    __shared__ float As[64][17];
    __shared__ float Bs[16][65];

    const int tid = threadIdx.x;
    const int tx = tid & 15;
    const int ty = tid >> 4;
    const int rowBase = blockIdx.x * 64;
    const int colBase = blockIdx.y * 64;

    float acc[4][4] = {};

    for (int k0 = 0; k0 < C_; k0 += 16) {
        {
            const int r = tid >> 2;
            const int c = (tid & 3) * 4;
            const float4 v = *(const float4*)&X[(size_t)(rowBase + r) * C_ + k0 + c];
            As[r][c + 0] = v.x; As[r][c + 1] = v.y; As[r][c + 2] = v.z; As[r][c + 3] = v.w;
        }
        {
            const int j = tid >> 2;
            const int c = (tid & 3) * 4;
            const float4 v = *(const float4*)&W[(size_t)(colBase + j) * C_ + k0 + c];
            Bs[c + 0][j] = v.x; Bs[c + 1][j] = v.y; Bs[c + 2][j] = v.z; Bs[c + 3][j] = v.w;
        }
        __syncthreads();
        #pragma unroll
        for (int kk = 0; kk < 16; ++kk) {
            float a[4], b[4];
            #pragma unroll
            for (int i = 0; i < 4; ++i) a[i] = As[ty * 4 + i][kk];
            #pragma unroll
            for (int j = 0; j < 4; ++j) b[j] = Bs[kk][tx * 4 + j];
            #pragma unroll
            for (int i = 0; i < 4; ++i)
                #pragma unroll
                for (int j = 0; j < 4; ++j)
                    acc[i][j] = fmaf(a[i], b[j], acc[i][j]);
        }
        __syncthreads();
    }

    #pragma unroll
    for (int i = 0; i < 4; ++i) {
        const int r = rowBase + ty * 4 + i;
        const int n = r >> 11, t = r & (T_ - 1);
        #pragma unroll
        for (int j = 0; j < 4; ++j) {
            const int cc = colBase + tx * 4 + j;
            const int h = cc >> 6, d = cc & 63;
            Y[((size_t)((n * H_ + h) * T_ + t)) * D_ + d] = f2bf(acc[i][j]);
        }
    }
}

// ---------------------------------------------------------------------------
// Kernel 2: MFMA bf16 flash attention.
// Grid: (T/64 q-tiles, N*H heads). Block: 256 threads = 4 waves.
// Wave w owns q-rows [qb + 16w, qb + 16w + 16). k-tiles of 32 keys.
// mfma_f32_16x16x32_bf16 layouts (m89-verified):
//   A: lane l holds A[l&15][(l>>4)*8 + j]          (16B contiguous)
//   B: lane l holds B[(l>>4)*8 + j][l&15]
//   C/D: lane l reg r -> row=(l>>4)*4+r, col=l&15
// ---------------------------------------------------------------------------
#define VT_STRIDE 40   // 64 x 40 bf16, 80B rows: 16B-aligned, <=2-way banks
#define PL_STRIDE 40

__global__ __launch_bounds__(256) void attn_mfma(const unsigned short* __restrict__ qg,
                                                 const unsigned short* __restrict__ kg,
                                                 const unsigned short* __restrict__ vg,
                                                 float* __restrict__ ob) {
    __shared__ __align__(16) unsigned short VT[64 * VT_STRIDE];       // V^T tile [d][k]
    __shared__ __align__(16) unsigned short PL[4][16 * PL_STRIDE];    // per-wave P tile

    const int tid  = threadIdx.x;
    const int w    = tid >> 6;        // wave id 0..3
    const int lane = tid & 63;
    const int lo   = lane & 15;
    const int hi   = lane >> 4;       // 0..3
    const int qb   = blockIdx.x * 64;
    const int nh   = blockIdx.y;
    const size_t base = (size_t)nh * T_ * D_;
    const int qrow0 = qb + w * 16;    // wave's first q row

    // Q fragments (2 d-chunks of 32), held for the whole kernel
    bf16x8 qf0 = *(const bf16x8*)(qg + base + (size_t)(qrow0 + lo) * D_ + 0 * 32 + hi * 8);
    bf16x8 qf1 = *(const bf16x8*)(qg + base + (size_t)(qrow0 + lo) * D_ + 1 * 32 + hi * 8);

    f32x4 o[4];
    #pragma unroll
    for (int i = 0; i < 4; ++i) o[i] = (f32x4)(0.f);
    float mrun[4] = {-INFINITY, -INFINITY, -INFINITY, -INFINITY};
    float lrun[4] = {0.f, 0.f, 0.f, 0.f};

    const int nkt = (qb >> 5) + 2;    // k-tiles of 32: covers cols <= qb+63
    const float SCALE = 0.03125f;     // 1/sqrt(1024)

    for (int kt = 0; kt < nkt; ++kt) {
        const int kbase = kt * 32;

        // ---- cooperative V^T staging (32 k-rows x 64 d), swizzled ----
        {
            const int krow = tid >> 3;          // 0..31
            const int a    = tid & 7;           // d-chunk (8 bf16)
            unsigned short vv[8];
            *(uint4*)vv = *(const uint4*)(vg + base + (size_t)(kbase + krow) * D_ + a * 8);
            const int kswl = krow & 7;
            const int kgrp = krow >> 3;         // == wave id
            #pragma unroll
            for (int j = 0; j < 8; ++j) {
                const int d = a * 8 + j;
                const int ks = (((kgrp ^ ((d >> 3) & 3)) << 3) | kswl);
                VT[d * VT_STRIDE + ks] = vv[j];
            }
        }
        __syncthreads();

        // ---- S = Q K^T (16x32), 4 MFMAs ----
        f32x4 s0 = (f32x4)(0.f), s1 = (f32x4)(0.f);
        {
            const bf16x8 kf00 = *(const bf16x8*)(kg + base + (size_t)(kbase + lo) * D_ + 0 + hi * 8);
            const bf16x8 kf01 = *(const bf16x8*)(kg + base + (size_t)(kbase + lo) * D_ + 32 + hi * 8);
            const bf16x8 kf10 = *(const bf16x8*)(kg + base + (size_t)(kbase + 16 + lo) * D_ + 0 + hi * 8);
            const bf16x8 kf11 = *(const bf16x8*)(kg + base + (size_t)(kbase + 16 + lo) * D_ + 32 + hi * 8);
            s0 = __builtin_amdgcn_mfma_f32_16x16x32_bf16(qf0, kf00, s0, 0, 0, 0);
            s0 = __builtin_amdgcn_mfma_f32_16x16x32_bf16(qf1, kf01, s0, 0, 0, 0);
            s1 = __builtin_amdgcn_mfma_f32_16x16x32_bf16(qf0, kf10, s1, 0, 0, 0);
            s1 = __builtin_amdgcn_mfma_f32_16x16x32_bf16(qf1, kf11, s1, 0, 0, 0);
        }

        // ---- online softmax (rows = qrow0 + hi*4 + r, cols = kbase + cb*16 + lo) ----
        #pragma unroll
        for (int r = 0; r < 4; ++r) {
            const int row = qrow0 + hi * 4 + r;
            const int c0 = kbase + lo;
            const int c1 = c0 + 16;
            float v0 = s0[r] * SCALE;
            float v1 = s1[r] * SCALE;
            const bool msk0 = c0 > row;
            const bool msk1 = c1 > row;
            v0 = msk0 ? -1e30f : v0;
            v1 = msk1 ? -1e30f : v1;
            float tm = fmaxf(v0, v1);
            tm = fmaxf(tm, __shfl_xor(tm, 1));
            tm = fmaxf(tm, __shfl_xor(tm, 2));
            tm = fmaxf(tm, __shfl_xor(tm, 4));
            tm = fmaxf(tm, __shfl_xor(tm, 8));
            const float mnew = fmaxf(mrun[r], tm);
            const float fsc = __expf(mrun[r] - mnew);
            const float p0 = msk0 ? 0.f : __expf(v0 - mnew);
            const float p1 = msk1 ? 0.f : __expf(v1 - mnew);
            float tsum = p0 + p1;
            tsum += __shfl_xor(tsum, 1);
            tsum += __shfl_xor(tsum, 2);
            tsum += __shfl_xor(tsum, 4);
            tsum += __shfl_xor(tsum, 8);
            lrun[r] = lrun[r] * fsc + tsum;
            mrun[r] = mnew;
            #pragma unroll
            for (int ds = 0; ds < 4; ++ds) o[ds][r] *= fsc;
            const int prow = hi * 4 + r;
            PL[w][prow * PL_STRIDE + lo]      = f2bf(p0);
            PL[w][prow * PL_STRIDE + 16 + lo] = f2bf(p1);
        }

        // ---- O += P V (4 MFMAs over d-subtiles) ----
        {
            const bf16x8 pa = *(const bf16x8*)&PL[w][lo * PL_STRIDE + hi * 8];
            #pragma unroll
            for (int ds = 0; ds < 4; ++ds) {
                const int d = ds * 16 + lo;
                const bf16x8 vf = *(const bf16x8*)&VT[d * VT_STRIDE + ((hi ^ ((d >> 3) & 3)) << 3)];
                o[ds] = __builtin_amdgcn_mfma_f32_16x16x32_bf16(pa, vf, o[ds], 0, 0, 0);
            }
        }
        __syncthreads();
    }

    // ---- epilogue: normalize, write fp32 [NH,T,D] ----
    #pragma unroll
    for (int r = 0; r < 4; ++r) {
        const float inv = 1.f / lrun[r];
        const int row = qrow0 + hi * 4 + r;
        #pragma unroll
        for (int ds = 0; ds < 4; ++ds) {
            ob[base + (size_t)row * D_ + ds * 16 + lo] = o[ds][r] * inv;
        }
    }
}

// ---------------------------------------------------------------------------
// Kernel 3: out = attn_out @ Wo^T + bo (attn_out fp32 in [N*H,T,D] layout).
// ---------------------------------------------------------------------------
__global__ __launch_bounds__(256) void out_gemm(const float* __restrict__ A,
                                                const float* __restrict__ Wo,
                                                const float* __restrict__ bo,
                                                float* __restrict__ out) {
    __shared__ float As[64][17];
    __shared__ float Bs[16][65];

    const int tid = threadIdx.x;
    const int tx = tid & 15;
    const int ty = tid >> 4;
    const int rowBase = blockIdx.x * 64;
    const int colBase = blockIdx.y * 64;

    float acc[4][4] = {};

    for (int k0 = 0; k0 < C_; k0 += 16) {
        {
            const int r = rowBase + (tid >> 2);
            const int c = k0 + (tid & 3) * 4;
            const int n = r >> 11, t = r & (T_ - 1);
            const int h = c >> 6, d = c & 63;
            const float4 v = *(const float4*)&A[((size_t)((n * H_ + h) * T_ + t)) * D_ + d];
            const int rr = tid >> 2, cc = (tid & 3) * 4;
            As[rr][cc + 0] = v.x; As[rr][cc + 1] = v.y; As[rr][cc + 2] = v.z; As[rr][cc + 3] = v.w;
        }
        {
            const int j = tid >> 2;
            const int c = (tid & 3) * 4;
            const float4 v = *(const float4*)&Wo[(size_t)(colBase + j) * C_ + k0 + c];
            Bs[c + 0][j] = v.x; Bs[c + 1][j] = v.y; Bs[c + 2][j] = v.z; Bs[c + 3][j] = v.w;
        }
        __syncthreads();
        #pragma unroll
        for (int kk = 0; kk < 16; ++kk) {
            float a[4], b[4];
            #pragma unroll
            for (int i = 0; i < 4; ++i) a[i] = As[ty * 4 + i][kk];
            #pragma unroll
            for (int j = 0; j < 4; ++j) b[j] = Bs[kk][tx * 4 + j];
            #pragma unroll
            for (int i = 0; i < 4; ++i)
                #pragma unroll
                for (int j = 0; j < 4; ++j)
                    acc[i][j] = fmaf(a[i], b[j], acc[i][j]);
        }
        __syncthreads();
    }

    #pragma unroll
    for (int i = 0; i < 4; ++i) {
        const int r = rowBase + ty * 4 + i;
        #pragma unroll
        for (int j = 0; j < 4; ++j) {
            const int cc = colBase + tx * 4 + j;
            out[(size_t)r * C_ + cc] = acc[i][j] + bo[cc];
        }
    }
}

// ---------------------------------------------------------------------------
extern "C" void kernel_launch(void* const* d_in, const int* in_sizes, int n_in,
                              void* d_out, int out_size, void* d_ws, size_t ws_size,
                              hipStream_t stream) {
    const float* x  = (const float*)d_in[0];
    const float* Wq = (const float*)d_in[1];
    const float* Wk = (const float*)d_in[2];
    const float* Wv = (const float*)d_in[3];
    const float* Wo = (const float*)d_in[4];
    const float* bo = (const float*)d_in[5];
    float* out = (float*)d_out;

    unsigned short* q_bf = (unsigned short*)d_ws;          // NTC bf16
    unsigned short* k_bf = q_bf + (size_t)NTC;
    unsigned short* v_bf = k_bf + (size_t)NTC;
    float* a_buf = (float*)(v_bf + (size_t)NTC);           // NTC fp32

    dim3 g1(N_ * T_ / 64, C_ / 64, 3);
    qkv_gemm<<<g1, 256, 0, stream>>>(x, Wq, Wk, Wv, q_bf);

    dim3 g2(T_ / 64, N_ * H_);
    attn_mfma<<<g2, 256, 0, stream>>>(q_bf, k_bf, v_bf, a_buf);

    dim3 g3(N_ * T_ / 64, C_ / 64);
    out_gemm<<<g3, 256, 0, stream>>>(a_buf, Wo, bo, out);
}

// Round 3
// 473.679 us; speedup vs baseline: 12.2827x; 3.4314x over previous
//
#include <hip/hip_runtime.h>
#include <math.h>

#define N_ 4
#define T_ 2048
#define C_ 1024
#define H_ 16
#define D_ 64
#define NTC (N_*T_*C_)   // 8388608
#define WELEM (C_*C_)    // 1048576 per weight matrix

typedef float f32x4 __attribute__((ext_vector_type(4)));
typedef short bf16x8 __attribute__((ext_vector_type(8)));

static __device__ __forceinline__ unsigned short f2bf(float f) {
    union { float f; unsigned u; } v; v.f = f;
    unsigned r = v.u + 0x7FFFu + ((v.u >> 16) & 1u);   // RNE
    return (unsigned short)(r >> 16);
}

#define GLDS16(gptr, lptr) \
    __builtin_amdgcn_global_load_lds((const __attribute__((address_space(1))) void*)(gptr), \
                                     (__attribute__((address_space(3))) void*)(lptr), 16, 0, 0)

// ---------------------------------------------------------------------------
// Cast kernels: fp32 -> bf16, 8 elems/thread.
// ---------------------------------------------------------------------------
__global__ __launch_bounds__(256) void cast_x(const float* __restrict__ src,
                                              unsigned short* __restrict__ dst) {
    const int i = blockIdx.x * 256 + threadIdx.x;
    const float4 a = ((const float4*)src)[i * 2];
    const float4 b = ((const float4*)src)[i * 2 + 1];
    unsigned short u[8] = {f2bf(a.x), f2bf(a.y), f2bf(a.z), f2bf(a.w),
                           f2bf(b.x), f2bf(b.y), f2bf(b.z), f2bf(b.w)};
    *(uint4*)&dst[(size_t)i * 8] = *(const uint4*)u;
}

__global__ __launch_bounds__(256) void cast_w4(const float* __restrict__ w0,
                                               const float* __restrict__ w1,
                                               const float* __restrict__ w2,
                                               const float* __restrict__ w3,
                                               unsigned short* __restrict__ dst) {
    const int z = blockIdx.y;
    const float* __restrict__ src = (z == 0) ? w0 : (z == 1) ? w1 : (z == 2) ? w2 : w3;
    unsigned short* __restrict__ d = dst + (size_t)z * WELEM;
    const int i = blockIdx.x * 256 + threadIdx.x;
    const float4 a = ((const float4*)src)[i * 2];
    const float4 b = ((const float4*)src)[i * 2 + 1];
    unsigned short u[8] = {f2bf(a.x), f2bf(a.y), f2bf(a.z), f2bf(a.w),
                           f2bf(b.x), f2bf(b.y), f2bf(b.z), f2bf(b.w)};
    *(uint4*)&d[(size_t)i * 8] = *(const uint4*)u;
}

// ---------------------------------------------------------------------------
// bf16 MFMA GEMM, m97 structure: 128x128 tile, BK=32, 4 waves (2x2), 4x4
// 16x16 fragments per wave. A [M][1024] bf16 row-major; B = W [1024][1024]
// bf16 row-major (used as B^T: C[m][n] = sum_k A[m][k]*W[n][k]).
// LDS linear [row][4 chunks of 8]; chunk swizzle slot = want ^ ((row>>1)&3)
// applied on global source at stage time and on ds_read (rule #21).
// EPI=0: write bf16 to Y in [NH,T,D] layout (qkv).
// EPI=1: write fp32 out[r*C+col] + bo[col] (out projection).
// ---------------------------------------------------------------------------
template <int EPI>
__global__ __launch_bounds__(256) void gemm_bf16(const unsigned short* __restrict__ A,
                                                 const unsigned short* __restrict__ B,
                                                 const float* __restrict__ bo,
                                                 void* __restrict__ outp) {
    __shared__ __align__(16) unsigned short Abuf[128 * 32];
    __shared__ __align__(16) unsigned short Bbuf[128 * 32];

    const int tid  = threadIdx.x;
    const int lane = tid & 63;
    const int w    = tid >> 6;
    const int lo   = lane & 15;
    const int hi   = lane >> 4;
    const int wm   = w >> 1;         // 0..1
    const int wn   = w & 1;          // 0..1
    const int rowBase = blockIdx.x * 128;
    const int colBase = blockIdx.y * 128;

    f32x4 acc[4][4];
    #pragma unroll
    for (int i = 0; i < 4; ++i)
        #pragma unroll
        for (int j = 0; j < 4; ++j) acc[i][j] = (f32x4)(0.f);

    // staging indices for this thread (2 chunks of A, 2 of B)
    const int i0 = tid, i1 = tid + 256;
    const int r0 = i0 >> 2, s0 = i0 & 3, g0 = s0 ^ ((r0 >> 1) & 3);
    const int r1 = i1 >> 2, s1 = i1 & 3, g1 = s1 ^ ((r1 >> 1) & 3);

    const unsigned short* gA0 = A + (size_t)(rowBase + r0) * C_ + g0 * 8;
    const unsigned short* gA1 = A + (size_t)(rowBase + r1) * C_ + g1 * 8;
    const unsigned short* gB0 = B + (size_t)(colBase + r0) * C_ + g0 * 8;
    const unsigned short* gB1 = B + (size_t)(colBase + r1) * C_ + g1 * 8;

    for (int k0 = 0; k0 < C_; k0 += 32) {
        GLDS16(gA0 + k0, &Abuf[i0 * 8]);
        GLDS16(gA1 + k0, &Abuf[i1 * 8]);
        GLDS16(gB0 + k0, &Bbuf[i0 * 8]);
        GLDS16(gB1 + k0, &Bbuf[i1 * 8]);
        __syncthreads();

        bf16x8 af[4], bf[4];
        #pragma unroll
        for (int mi = 0; mi < 4; ++mi) {
            const int row = wm * 64 + mi * 16 + lo;
            const int slot = hi ^ ((row >> 1) & 3);
            af[mi] = *(const bf16x8*)&Abuf[row * 32 + slot * 8];
        }
        #pragma unroll
        for (int ni = 0; ni < 4; ++ni) {
            const int row = wn * 64 + ni * 16 + lo;
            const int slot = hi ^ ((row >> 1) & 3);
            bf[ni] = *(const bf16x8*)&Bbuf[row * 32 + slot * 8];
        }
        #pragma unroll
        for (int mi = 0; mi < 4; ++mi)
            #pragma unroll
            for (int ni = 0; ni < 4; ++ni)
                acc[mi][ni] = __builtin_amdgcn_mfma_f32_16x16x32_bf16(af[mi], bf[ni], acc[mi][ni], 0, 0, 0);
        __syncthreads();
    }

    if (EPI == 0) {
        unsigned short* __restrict__ Y = (unsigned short*)outp;
        #pragma unroll
        for (int mi = 0; mi < 4; ++mi) {
            #pragma unroll
            for (int r = 0; r < 4; ++r) {
                const int row = rowBase + wm * 64 + mi * 16 + hi * 4 + r;
                const int nn = row >> 11, tt = row & (T_ - 1);
                #pragma unroll
                for (int ni = 0; ni < 4; ++ni) {
                    const int col = colBase + wn * 64 + ni * 16 + lo;
                    const int hh = col >> 6, dd = col & 63;
                    Y[((size_t)((nn * H_ + hh) * T_ + tt)) * D_ + dd] = f2bf(acc[mi][ni][r]);
                }
            }
        }
    } else {
        float* __restrict__ out = (float*)outp;
        float bias[4];
        #pragma unroll
        for (int ni = 0; ni < 4; ++ni) bias[ni] = bo[colBase + wn * 64 + ni * 16 + lo];
        #pragma unroll
        for (int mi = 0; mi < 4; ++mi) {
            #pragma unroll
            for (int r = 0; r < 4; ++r) {
                const int row = rowBase + wm * 64 + mi * 16 + hi * 4 + r;
                #pragma unroll
                for (int ni = 0; ni < 4; ++ni) {
                    const int col = colBase + wn * 64 + ni * 16 + lo;
                    out[(size_t)row * C_ + col] = acc[mi][ni][r] + bias[ni];
                }
            }
        }
    }
}

// ---------------------------------------------------------------------------
// MFMA bf16 flash attention (unchanged core from round 2); epilogue now
// writes bf16 in [N*T, C] row-major so the out-projection GEMM reads it as a
// plain A matrix.
// ---------------------------------------------------------------------------
#define VT_STRIDE 40
#define PL_STRIDE 40

__global__ __launch_bounds__(256) void attn_mfma(const unsigned short* __restrict__ qg,
                                                 const unsigned short* __restrict__ kg,
                                                 const unsigned short* __restrict__ vg,
                                                 unsigned short* __restrict__ ob) {
    __shared__ __align__(16) unsigned short VT[64 * VT_STRIDE];
    __shared__ __align__(16) unsigned short PL[4][16 * PL_STRIDE];

    const int tid  = threadIdx.x;
    const int w    = tid >> 6;
    const int lane = tid & 63;
    const int lo   = lane & 15;
    const int hi   = lane >> 4;
    const int qb   = blockIdx.x * 64;
    const int nh   = blockIdx.y;
    const size_t base = (size_t)nh * T_ * D_;
    const int qrow0 = qb + w * 16;

    bf16x8 qf0 = *(const bf16x8*)(qg + base + (size_t)(qrow0 + lo) * D_ + 0 * 32 + hi * 8);
    bf16x8 qf1 = *(const bf16x8*)(qg + base + (size_t)(qrow0 + lo) * D_ + 1 * 32 + hi * 8);

    f32x4 o[4];
    #pragma unroll
    for (int i = 0; i < 4; ++i) o[i] = (f32x4)(0.f);
    float mrun[4] = {-INFINITY, -INFINITY, -INFINITY, -INFINITY};
    float lrun[4] = {0.f, 0.f, 0.f, 0.f};

    const int nkt = (qb >> 5) + 2;
    const float SCALE = 0.03125f;

    for (int kt = 0; kt < nkt; ++kt) {
        const int kbase = kt * 32;

        {
            const int krow = tid >> 3;
            const int a    = tid & 7;
            unsigned short vv[8];
            *(uint4*)vv = *(const uint4*)(vg + base + (size_t)(kbase + krow) * D_ + a * 8);
            const int kswl = krow & 7;
            const int kgrp = krow >> 3;
            #pragma unroll
            for (int j = 0; j < 8; ++j) {
                const int d = a * 8 + j;
                const int ks = (((kgrp ^ ((d >> 3) & 3)) << 3) | kswl);
                VT[d * VT_STRIDE + ks] = vv[j];
            }
        }
        __syncthreads();

        f32x4 s0 = (f32x4)(0.f), s1 = (f32x4)(0.f);
        {
            const bf16x8 kf00 = *(const bf16x8*)(kg + base + (size_t)(kbase + lo) * D_ + 0 + hi * 8);
            const bf16x8 kf01 = *(const bf16x8*)(kg + base + (size_t)(kbase + lo) * D_ + 32 + hi * 8);
            const bf16x8 kf10 = *(const bf16x8*)(kg + base + (size_t)(kbase + 16 + lo) * D_ + 0 + hi * 8);
            const bf16x8 kf11 = *(const bf16x8*)(kg + base + (size_t)(kbase + 16 + lo) * D_ + 32 + hi * 8);
            s0 = __builtin_amdgcn_mfma_f32_16x16x32_bf16(qf0, kf00, s0, 0, 0, 0);
            s0 = __builtin_amdgcn_mfma_f32_16x16x32_bf16(qf1, kf01, s0, 0, 0, 0);
            s1 = __builtin_amdgcn_mfma_f32_16x16x32_bf16(qf0, kf10, s1, 0, 0, 0);
            s1 = __builtin_amdgcn_mfma_f32_16x16x32_bf16(qf1, kf11, s1, 0, 0, 0);
        }

        #pragma unroll
        for (int r = 0; r < 4; ++r) {
            const int row = qrow0 + hi * 4 + r;
            const int c0 = kbase + lo;
            const int c1 = c0 + 16;
            float v0 = s0[r] * SCALE;
            float v1 = s1[r] * SCALE;
            const bool msk0 = c0 > row;
            const bool msk1 = c1 > row;
            v0 = msk0 ? -1e30f : v0;
            v1 = msk1 ? -1e30f : v1;
            float tm = fmaxf(v0, v1);
            tm = fmaxf(tm, __shfl_xor(tm, 1));
            tm = fmaxf(tm, __shfl_xor(tm, 2));
            tm = fmaxf(tm, __shfl_xor(tm, 4));
            tm = fmaxf(tm, __shfl_xor(tm, 8));
            const float mnew = fmaxf(mrun[r], tm);
            const float fsc = __expf(mrun[r] - mnew);
            const float p0 = msk0 ? 0.f : __expf(v0 - mnew);
            const float p1 = msk1 ? 0.f : __expf(v1 - mnew);
            float tsum = p0 + p1;
            tsum += __shfl_xor(tsum, 1);
            tsum += __shfl_xor(tsum, 2);
            tsum += __shfl_xor(tsum, 4);
            tsum += __shfl_xor(tsum, 8);
            lrun[r] = lrun[r] * fsc + tsum;
            mrun[r] = mnew;
            #pragma unroll
            for (int ds = 0; ds < 4; ++ds) o[ds][r] *= fsc;
            const int prow = hi * 4 + r;
            PL[w][prow * PL_STRIDE + lo]      = f2bf(p0);
            PL[w][prow * PL_STRIDE + 16 + lo] = f2bf(p1);
        }

        {
            const bf16x8 pa = *(const bf16x8*)&PL[w][lo * PL_STRIDE + hi * 8];
            #pragma unroll
            for (int ds = 0; ds < 4; ++ds) {
                const int d = ds * 16 + lo;
                const bf16x8 vf = *(const bf16x8*)&VT[d * VT_STRIDE + ((hi ^ ((d >> 3) & 3)) << 3)];
                o[ds] = __builtin_amdgcn_mfma_f32_16x16x32_bf16(pa, vf, o[ds], 0, 0, 0);
            }
        }
        __syncthreads();
    }

    // epilogue: bf16 write in [N*T, C] row-major (r = n*T+t, c = h*64+d)
    const int nn = nh >> 4;          // / H
    const int hh = nh & (H_ - 1);
    #pragma unroll
    for (int r = 0; r < 4; ++r) {
        const float inv = 1.f / lrun[r];
        const int row = qrow0 + hi * 4 + r;
        #pragma unroll
        for (int ds = 0; ds < 4; ++ds) {
            ob[(size_t)(nn * T_ + row) * C_ + hh * 64 + ds * 16 + lo] = f2bf(o[ds][r] * inv);
        }
    }
}

// ---------------------------------------------------------------------------
extern "C" void kernel_launch(void* const* d_in, const int* in_sizes, int n_in,
                              void* d_out, int out_size, void* d_ws, size_t ws_size,
                              hipStream_t stream) {
    const float* x  = (const float*)d_in[0];
    const float* Wq = (const float*)d_in[1];
    const float* Wk = (const float*)d_in[2];
    const float* Wv = (const float*)d_in[3];
    const float* Wo = (const float*)d_in[4];
    const float* bo = (const float*)d_in[5];
    float* out = (float*)d_out;

    unsigned short* ws = (unsigned short*)d_ws;
    unsigned short* x_bf = ws;                              // NTC
    unsigned short* w_bf = x_bf + (size_t)NTC;              // 4*WELEM
    unsigned short* q_bf = w_bf + (size_t)4 * WELEM;        // NTC
    unsigned short* k_bf = q_bf + (size_t)NTC;              // NTC
    unsigned short* v_bf = k_bf + (size_t)NTC;              // NTC
    unsigned short* a_bf = v_bf + (size_t)NTC;              // NTC

    cast_x<<<NTC / (8 * 256), 256, 0, stream>>>(x, x_bf);
    dim3 gw(WELEM / (8 * 256), 4);
    cast_w4<<<gw, 256, 0, stream>>>(Wq, Wk, Wv, Wo, w_bf);

    // Q/K/V projections: one dispatch per matrix (same kernel, EPI=0)
    dim3 gg(N_ * T_ / 128, C_ / 128);
    gemm_bf16<0><<<gg, 256, 0, stream>>>(x_bf, w_bf + 0 * (size_t)WELEM, nullptr, q_bf);
    gemm_bf16<0><<<gg, 256, 0, stream>>>(x_bf, w_bf + 1 * (size_t)WELEM, nullptr, k_bf);
    gemm_bf16<0><<<gg, 256, 0, stream>>>(x_bf, w_bf + 2 * (size_t)WELEM, nullptr, v_bf);

    dim3 g2(T_ / 64, N_ * H_);
    attn_mfma<<<g2, 256, 0, stream>>>(q_bf, k_bf, v_bf, a_bf);

    gemm_bf16<1><<<gg, 256, 0, stream>>>(a_bf, w_bf + 3 * (size_t)WELEM, bo, out);
}

// Round 4
// 282.668 us; speedup vs baseline: 20.5826x; 1.6757x over previous
//
#include <hip/hip_runtime.h>
#include <math.h>

#define N_ 4
#define T_ 2048
#define C_ 1024
#define H_ 16
#define D_ 64
#define NTC (N_*T_*C_)   // 8388608
#define WELEM (C_*C_)    // 1048576 per weight matrix

typedef float f32x4 __attribute__((ext_vector_type(4)));
typedef short bf16x8 __attribute__((ext_vector_type(8)));

static __device__ __forceinline__ unsigned short f2bf(float f) {
    union { float f; unsigned u; } v; v.f = f;
    unsigned r = v.u + 0x7FFFu + ((v.u >> 16) & 1u);   // RNE
    return (unsigned short)(r >> 16);
}

#define GLDS16(gptr, lptr) \
    __builtin_amdgcn_global_load_lds((const __attribute__((address_space(1))) void*)(gptr), \
                                     (__attribute__((address_space(3))) void*)(lptr), 16, 0, 0)

// ---------------------------------------------------------------------------
// Cast kernels: fp32 -> bf16, 8 elems/thread.
// ---------------------------------------------------------------------------
__global__ __launch_bounds__(256) void cast_x(const float* __restrict__ src,
                                              unsigned short* __restrict__ dst) {
    const int i = blockIdx.x * 256 + threadIdx.x;
    const float4 a = ((const float4*)src)[i * 2];
    const float4 b = ((const float4*)src)[i * 2 + 1];
    unsigned short u[8] = {f2bf(a.x), f2bf(a.y), f2bf(a.z), f2bf(a.w),
                           f2bf(b.x), f2bf(b.y), f2bf(b.z), f2bf(b.w)};
    *(uint4*)&dst[(size_t)i * 8] = *(const uint4*)u;
}

__global__ __launch_bounds__(256) void cast_w4(const float* __restrict__ w0,
                                               const float* __restrict__ w1,
                                               const float* __restrict__ w2,
                                               const float* __restrict__ w3,
                                               unsigned short* __restrict__ dst) {
    const int z = blockIdx.y;
    const float* __restrict__ src = (z == 0) ? w0 : (z == 1) ? w1 : (z == 2) ? w2 : w3;
    unsigned short* __restrict__ d = dst + (size_t)z * WELEM;
    const int i = blockIdx.x * 256 + threadIdx.x;
    const float4 a = ((const float4*)src)[i * 2];
    const float4 b = ((const float4*)src)[i * 2 + 1];
    unsigned short u[8] = {f2bf(a.x), f2bf(a.y), f2bf(a.z), f2bf(a.w),
                           f2bf(b.x), f2bf(b.y), f2bf(b.z), f2bf(b.w)};
    *(uint4*)&d[(size_t)i * 8] = *(const uint4*)u;
}

// ---------------------------------------------------------------------------
// bf16 MFMA GEMM (m97 structure): 128x128 tile, BK=32, 4 waves, 4x4 frags.
// EPI=0: write bf16 (acc*oscale) to [NH,T,D] layout. EPI=1: fp32 + bias.
// ---------------------------------------------------------------------------
template <int EPI>
__global__ __launch_bounds__(256) void gemm_bf16(const unsigned short* __restrict__ A,
                                                 const unsigned short* __restrict__ B,
                                                 const float* __restrict__ bo,
                                                 void* __restrict__ outp,
                                                 float oscale) {
    __shared__ __align__(16) unsigned short Abuf[128 * 32];
    __shared__ __align__(16) unsigned short Bbuf[128 * 32];

    const int tid  = threadIdx.x;
    const int lane = tid & 63;
    const int w    = tid >> 6;
    const int lo   = lane & 15;
    const int hi   = lane >> 4;
    const int wm   = w >> 1;
    const int wn   = w & 1;
    const int rowBase = blockIdx.x * 128;
    const int colBase = blockIdx.y * 128;

    f32x4 acc[4][4];
    #pragma unroll
    for (int i = 0; i < 4; ++i)
        #pragma unroll
        for (int j = 0; j < 4; ++j) acc[i][j] = (f32x4)(0.f);

    const int i0 = tid, i1 = tid + 256;
    const int r0 = i0 >> 2, s0 = i0 & 3, g0 = s0 ^ ((r0 >> 1) & 3);
    const int r1 = i1 >> 2, s1 = i1 & 3, g1 = s1 ^ ((r1 >> 1) & 3);

    const unsigned short* gA0 = A + (size_t)(rowBase + r0) * C_ + g0 * 8;
    const unsigned short* gA1 = A + (size_t)(rowBase + r1) * C_ + g1 * 8;
    const unsigned short* gB0 = B + (size_t)(colBase + r0) * C_ + g0 * 8;
    const unsigned short* gB1 = B + (size_t)(colBase + r1) * C_ + g1 * 8;

    for (int k0 = 0; k0 < C_; k0 += 32) {
        GLDS16(gA0 + k0, &Abuf[i0 * 8]);
        GLDS16(gA1 + k0, &Abuf[i1 * 8]);
        GLDS16(gB0 + k0, &Bbuf[i0 * 8]);
        GLDS16(gB1 + k0, &Bbuf[i1 * 8]);
        __syncthreads();

        bf16x8 af[4], bf[4];
        #pragma unroll
        for (int mi = 0; mi < 4; ++mi) {
            const int row = wm * 64 + mi * 16 + lo;
            const int slot = hi ^ ((row >> 1) & 3);
            af[mi] = *(const bf16x8*)&Abuf[row * 32 + slot * 8];
        }
        #pragma unroll
        for (int ni = 0; ni < 4; ++ni) {
            const int row = wn * 64 + ni * 16 + lo;
            const int slot = hi ^ ((row >> 1) & 3);
            bf[ni] = *(const bf16x8*)&Bbuf[row * 32 + slot * 8];
        }
        #pragma unroll
        for (int mi = 0; mi < 4; ++mi)
            #pragma unroll
            for (int ni = 0; ni < 4; ++ni)
                acc[mi][ni] = __builtin_amdgcn_mfma_f32_16x16x32_bf16(af[mi], bf[ni], acc[mi][ni], 0, 0, 0);
        __syncthreads();
    }

    if (EPI == 0) {
        unsigned short* __restrict__ Y = (unsigned short*)outp;
        #pragma unroll
        for (int mi = 0; mi < 4; ++mi) {
            #pragma unroll
            for (int r = 0; r < 4; ++r) {
                const int row = rowBase + wm * 64 + mi * 16 + hi * 4 + r;
                const int nn = row >> 11, tt = row & (T_ - 1);
                #pragma unroll
                for (int ni = 0; ni < 4; ++ni) {
                    const int col = colBase + wn * 64 + ni * 16 + lo;
                    const int hh = col >> 6, dd = col & 63;
                    Y[((size_t)((nn * H_ + hh) * T_ + tt)) * D_ + dd] = f2bf(acc[mi][ni][r] * oscale);
                }
            }
        }
    } else {
        float* __restrict__ out = (float*)outp;
        float bias[4];
        #pragma unroll
        for (int ni = 0; ni < 4; ++ni) bias[ni] = bo[colBase + wn * 64 + ni * 16 + lo];
        #pragma unroll
        for (int mi = 0; mi < 4; ++mi) {
            #pragma unroll
            for (int r = 0; r < 4; ++r) {
                const int row = rowBase + wm * 64 + mi * 16 + hi * 4 + r;
                #pragma unroll
                for (int ni = 0; ni < 4; ++ni) {
                    const int col = colBase + wn * 64 + ni * 16 + lo;
                    out[(size_t)row * C_ + col] = acc[mi][ni][r] + bias[ni];
                }
            }
        }
    }
}

// ---------------------------------------------------------------------------
// MFMA flash attention, swapped-QK^T form.
// Grid: 1D 2048 blocks; qtile = 31 - bid/64 (longest first), nh = bid & 63.
// Block = 4 waves; wave w owns 16 q-rows. KV tile = 64 keys.
// S^T[k][q] = mfma(K_frag, Q_frag): lane (lo,hi) holds, per 16-k subtile c,
// scores for k = c*16 + hi*4 + r, q = lo. Softmax per-lane in-register +
// 2 shfl_xor (hi reduce). P -> LDS [q][k] (packed b64, XOR-swizzled);
// PV = mfma(P_frag, V^T_frag) as before. Q pre-scaled by 1/32 in projection.
// ---------------------------------------------------------------------------
__global__ __launch_bounds__(256) void attn_mfma(const unsigned short* __restrict__ qg,
                                                 const unsigned short* __restrict__ kg,
                                                 const unsigned short* __restrict__ vg,
                                                 unsigned short* __restrict__ ob) {
    __shared__ unsigned int VT32[64 * 32];              // V^T [d][k], granule-XOR by d&7
    __shared__ __align__(16) unsigned short PL[4][16 * 72];  // per-wave P [q][k], stride 72

    const int tid  = threadIdx.x;
    const int w    = tid >> 6;
    const int lane = tid & 63;
    const int lo   = lane & 15;
    const int hi   = lane >> 4;
    const int bid  = blockIdx.x;
    const int qtile = (T_ / 64 - 1) - (bid >> 6);
    const int nh   = bid & 63;
    const int qb   = qtile * 64;
    const size_t base = (size_t)nh * (T_ * D_);
    const int qrow0 = qb + w * 16;
    unsigned short* PLw = PL[w];

    const bf16x8 qf0 = *(const bf16x8*)(qg + base + (size_t)(qrow0 + lo) * D_ + hi * 8);
    const bf16x8 qf1 = *(const bf16x8*)(qg + base + (size_t)(qrow0 + lo) * D_ + 32 + hi * 8);

    f32x4 o[4];
    #pragma unroll
    for (int i = 0; i < 4; ++i) o[i] = (f32x4)(0.f);
    float mrun = -INFINITY, lrun = 0.f;

    // V staging assignment (fixed per thread): key pair k2, d-octet d0v.
    const int k2  = (lane & 31) * 2;
    const int d0v = w * 16 + (lane >> 5) * 8;
    const int kg3 = k2 >> 3;
    const int kq  = (k2 >> 1) & 3;

    const int nkt = qtile + 1;

    for (int kt = 0; kt < nkt; ++kt) {
        const bool diag = (kt == nkt - 1);
        const int kbase = kt * 64;
        const int csub = diag ? (w + 1) : 4;   // subtiles to compute (wave-uniform)

        __syncthreads();   // previous tile's PV reads done before VT overwrite

        // ---- stage V^T: 2 k-rows x 8 d each, packed-pair b32 writes ----
        {
            const unsigned short* vsrc = vg + base + (size_t)(kbase + k2) * D_ + d0v;
            const uint4 va = *(const uint4*)vsrc;
            const uint4 vb = *(const uint4*)(vsrc + D_);
            const unsigned short* va16 = (const unsigned short*)&va;
            const unsigned short* vb16 = (const unsigned short*)&vb;
            #pragma unroll
            for (int j = 0; j < 8; ++j) {
                VT32[(d0v + j) * 32 + ((kg3 ^ j) << 2) + kq] =
                    (unsigned)va16[j] | ((unsigned)vb16[j] << 16);
            }
        }

        // ---- S^T = K Q^T ----
        f32x4 s[4];
        __builtin_amdgcn_s_setprio(1);
        #pragma unroll
        for (int c = 0; c < 4; ++c) {
            if (c < csub) {
                const unsigned short* kr = kg + base + (size_t)(kbase + c * 16 + lo) * D_ + hi * 8;
                const bf16x8 ka = *(const bf16x8*)kr;
                const bf16x8 kb = *(const bf16x8*)(kr + 32);
                f32x4 z = (f32x4)(0.f);
                z = __builtin_amdgcn_mfma_f32_16x16x32_bf16(ka, qf0, z, 0, 0, 0);
                z = __builtin_amdgcn_mfma_f32_16x16x32_bf16(kb, qf1, z, 0, 0, 0);
                s[c] = z;
            }
        }
        __builtin_amdgcn_s_setprio(0);

        // ---- softmax: per-lane rows (q = lo), in-register ----
        float tm = -1e30f;
        #pragma unroll
        for (int c = 0; c < 4; ++c) {
            if (c < csub) {
                if (diag && c == w) {
                    #pragma unroll
                    for (int r = 0; r < 4; ++r)
                        if (hi * 4 + r > lo) s[c][r] = -1e30f;
                }
                #pragma unroll
                for (int r = 0; r < 4; ++r) tm = fmaxf(tm, s[c][r]);
            }
        }
        tm = fmaxf(tm, __shfl_xor(tm, 16));
        tm = fmaxf(tm, __shfl_xor(tm, 32));

        const bool re = !__all(tm <= mrun + 8.f);   // defer-max (T13)
        float fsc = 1.f;
        if (re) {
            const float mnew = fmaxf(mrun, tm);
            fsc = __expf(mrun - mnew);
            mrun = mnew;
        }

        float p[4][4];
        float psum = 0.f;
        #pragma unroll
        for (int c = 0; c < 4; ++c) {
            if (c < csub) {
                #pragma unroll
                for (int r = 0; r < 4; ++r) { p[c][r] = __expf(s[c][r] - mrun); psum += p[c][r]; }
            } else {
                #pragma unroll
                for (int r = 0; r < 4; ++r) p[c][r] = 0.f;
            }
        }
        psum += __shfl_xor(psum, 16);
        psum += __shfl_xor(psum, 32);
        lrun = lrun * fsc + psum;

        if (re) {
            float fo[4];
            #pragma unroll
            for (int r = 0; r < 4; ++r) fo[r] = __shfl(fsc, hi * 4 + r);
            #pragma unroll
            for (int ds = 0; ds < 4; ++ds)
                #pragma unroll
                for (int r = 0; r < 4; ++r) o[ds][r] *= fo[r];
        }

        // ---- P -> LDS [q=lo][k], packed b64, XOR-swizzled ----
        #pragma unroll
        for (int c = 0; c < 4; ++c) {
            const unsigned w0 = (unsigned)f2bf(p[c][0]) | ((unsigned)f2bf(p[c][1]) << 16);
            const unsigned w1 = (unsigned)f2bf(p[c][2]) | ((unsigned)f2bf(p[c][3]) << 16);
            const int idx = lo * 72 + ((c * 16 + hi * 4) ^ ((lo & 7) << 3));
            *(uint2*)&PLw[idx] = make_uint2(w0, w1);
        }
        __syncthreads();   // VT visible to all waves

        // ---- O += P V ----
        __builtin_amdgcn_s_setprio(1);
        #pragma unroll
        for (int ch = 0; ch < 2; ++ch) {
            const int pidx = lo * 72 + ((ch * 32 + hi * 8) ^ ((lo & 7) << 3));
            const bf16x8 pa = *(const bf16x8*)&PLw[pidx];
            #pragma unroll
            for (int ds = 0; ds < 4; ++ds) {
                const int d = ds * 16 + lo;
                const int g = (4 * ch + hi) ^ (d & 7);
                const bf16x8 vf = *(const bf16x8*)((const unsigned short*)VT32 + d * 64 + g * 8);
                o[ds] = __builtin_amdgcn_mfma_f32_16x16x32_bf16(pa, vf, o[ds], 0, 0, 0);
            }
        }
        __builtin_amdgcn_s_setprio(0);
    }

    // ---- epilogue: redistribute 1/l (held by q=lo lanes) to output rows ----
    const float linv = 1.f / lrun;
    float li[4];
    #pragma unroll
    for (int r = 0; r < 4; ++r) li[r] = __shfl(linv, hi * 4 + r);

    const int nn = nh >> 4;
    const int hh = nh & (H_ - 1);
    #pragma unroll
    for (int r = 0; r < 4; ++r) {
        const int row = qrow0 + hi * 4 + r;
        #pragma unroll
        for (int ds = 0; ds < 4; ++ds) {
            ob[(size_t)(nn * T_ + row) * C_ + hh * 64 + ds * 16 + lo] = f2bf(o[ds][r] * li[r]);
        }
    }
}

// ---------------------------------------------------------------------------
extern "C" void kernel_launch(void* const* d_in, const int* in_sizes, int n_in,
                              void* d_out, int out_size, void* d_ws, size_t ws_size,
                              hipStream_t stream) {
    const float* x  = (const float*)d_in[0];
    const float* Wq = (const float*)d_in[1];
    const float* Wk = (const float*)d_in[2];
    const float* Wv = (const float*)d_in[3];
    const float* Wo = (const float*)d_in[4];
    const float* bo = (const float*)d_in[5];
    float* out = (float*)d_out;

    unsigned short* ws = (unsigned short*)d_ws;
    unsigned short* x_bf = ws;
    unsigned short* w_bf = x_bf + (size_t)NTC;
    unsigned short* q_bf = w_bf + (size_t)4 * WELEM;
    unsigned short* k_bf = q_bf + (size_t)NTC;
    unsigned short* v_bf = k_bf + (size_t)NTC;
    unsigned short* a_bf = v_bf + (size_t)NTC;

    cast_x<<<NTC / (8 * 256), 256, 0, stream>>>(x, x_bf);
    dim3 gw(WELEM / (8 * 256), 4);
    cast_w4<<<gw, 256, 0, stream>>>(Wq, Wk, Wv, Wo, w_bf);

    dim3 gg(N_ * T_ / 128, C_ / 128);
    // Q projection pre-scales by 1/sqrt(C) = 1/32
    gemm_bf16<0><<<gg, 256, 0, stream>>>(x_bf, w_bf + 0 * (size_t)WELEM, nullptr, q_bf, 0.03125f);
    gemm_bf16<0><<<gg, 256, 0, stream>>>(x_bf, w_bf + 1 * (size_t)WELEM, nullptr, k_bf, 1.0f);
    gemm_bf16<0><<<gg, 256, 0, stream>>>(x_bf, w_bf + 2 * (size_t)WELEM, nullptr, v_bf, 1.0f);

    attn_mfma<<<(T_ / 64) * (N_ * H_), 256, 0, stream>>>(q_bf, k_bf, v_bf, a_bf);

    gemm_bf16<1><<<gg, 256, 0, stream>>>(a_bf, w_bf + 3 * (size_t)WELEM, bo, out, 1.0f);
}

// Round 6
// 182.802 us; speedup vs baseline: 31.8270x; 1.5463x over previous
//
#include <hip/hip_runtime.h>
#include <math.h>

#define N_ 4
#define T_ 2048
#define C_ 1024
#define H_ 16
#define D_ 64
#define NTC (N_*T_*C_)   // 8388608
#define WELEM (C_*C_)    // 1048576

typedef float f32x4  __attribute__((ext_vector_type(4)));
typedef float f32x16 __attribute__((ext_vector_type(16)));
typedef short bf16x8 __attribute__((ext_vector_type(8)));

static __device__ __forceinline__ unsigned short f2bf(float f) {
    union { float f; unsigned u; } v; v.f = f;
    unsigned r = v.u + 0x7FFFu + ((v.u >> 16) & 1u);   // RNE
    return (unsigned short)(r >> 16);
}

static __device__ __forceinline__ unsigned cvtpk(float lo, float hi) {
    unsigned r;
    asm("v_cvt_pk_bf16_f32 %0, %1, %2" : "=v"(r) : "v"(lo), "v"(hi));
    return r;
}
// v_permlane32_swap_b32 a, b: a.upper <-> b.lower.
// SAFE ONLY when a and b are distinct values (distinct registers)! With
// a==b the compiler coalesces them into one VGPR and the swap degenerates
// (round-5 bug). Scalar cross-half reductions use __shfl_xor instead.
#define PLSWAP(a, b) asm("v_permlane32_swap_b32 %0, %1" : "+v"(a), "+v"(b))

#define GLDS16(gptr, lptr) \
    __builtin_amdgcn_global_load_lds((const __attribute__((address_space(1))) void*)(gptr), \
                                     (__attribute__((address_space(3))) void*)(lptr), 16, 0, 0)

// ---------------------------------------------------------------------------
// fp32 -> bf16 casts
// ---------------------------------------------------------------------------
__global__ __launch_bounds__(256) void cast_x(const float* __restrict__ src,
                                              unsigned short* __restrict__ dst) {
    const int i = blockIdx.x * 256 + threadIdx.x;
    const float4 a = ((const float4*)src)[i * 2];
    const float4 b = ((const float4*)src)[i * 2 + 1];
    unsigned short u[8] = {f2bf(a.x), f2bf(a.y), f2bf(a.z), f2bf(a.w),
                           f2bf(b.x), f2bf(b.y), f2bf(b.z), f2bf(b.w)};
    *(uint4*)&dst[(size_t)i * 8] = *(const uint4*)u;
}

__global__ __launch_bounds__(256) void cast_w4(const float* __restrict__ w0,
                                               const float* __restrict__ w1,
                                               const float* __restrict__ w2,
                                               const float* __restrict__ w3,
                                               unsigned short* __restrict__ dst) {
    const int z = blockIdx.y;
    const float* __restrict__ src = (z == 0) ? w0 : (z == 1) ? w1 : (z == 2) ? w2 : w3;
    unsigned short* __restrict__ d = dst + (size_t)z * WELEM;
    const int i = blockIdx.x * 256 + threadIdx.x;
    const float4 a = ((const float4*)src)[i * 2];
    const float4 b = ((const float4*)src)[i * 2 + 1];
    unsigned short u[8] = {f2bf(a.x), f2bf(a.y), f2bf(a.z), f2bf(a.w),
                           f2bf(b.x), f2bf(b.y), f2bf(b.z), f2bf(b.w)};
    *(uint4*)&d[(size_t)i * 8] = *(const uint4*)u;
}

// ---------------------------------------------------------------------------
// bf16 MFMA GEMM (m97 structure). EPI=0: bf16 out, [NH,T,D] layout (Q/K).
// EPI=1: fp32 + bias, [M,C] (out projection). EPI=2: bf16 V^T, [NH*64+d][T].
// ---------------------------------------------------------------------------
template <int EPI>
__global__ __launch_bounds__(256) void gemm_bf16(const unsigned short* __restrict__ A,
                                                 const unsigned short* __restrict__ B,
                                                 const float* __restrict__ bo,
                                                 void* __restrict__ outp,
                                                 float oscale) {
    __shared__ __align__(16) unsigned short Abuf[128 * 32];
    __shared__ __align__(16) unsigned short Bbuf[128 * 32];

    const int tid  = threadIdx.x;
    const int lane = tid & 63;
    const int w    = tid >> 6;
    const int lo   = lane & 15;
    const int hi   = lane >> 4;
    const int wm   = w >> 1;
    const int wn   = w & 1;
    const int rowBase = blockIdx.x * 128;
    const int colBase = blockIdx.y * 128;

    f32x4 acc[4][4];
    #pragma unroll
    for (int i = 0; i < 4; ++i)
        #pragma unroll
        for (int j = 0; j < 4; ++j) acc[i][j] = (f32x4)(0.f);

    const int i0 = tid, i1 = tid + 256;
    const int r0 = i0 >> 2, s0 = i0 & 3, g0 = s0 ^ ((r0 >> 1) & 3);
    const int r1 = i1 >> 2, s1 = i1 & 3, g1 = s1 ^ ((r1 >> 1) & 3);

    const unsigned short* gA0 = A + (size_t)(rowBase + r0) * C_ + g0 * 8;
    const unsigned short* gA1 = A + (size_t)(rowBase + r1) * C_ + g1 * 8;
    const unsigned short* gB0 = B + (size_t)(colBase + r0) * C_ + g0 * 8;
    const unsigned short* gB1 = B + (size_t)(colBase + r1) * C_ + g1 * 8;

    for (int k0 = 0; k0 < C_; k0 += 32) {
        GLDS16(gA0 + k0, &Abuf[i0 * 8]);
        GLDS16(gA1 + k0, &Abuf[i1 * 8]);
        GLDS16(gB0 + k0, &Bbuf[i0 * 8]);
        GLDS16(gB1 + k0, &Bbuf[i1 * 8]);
        __syncthreads();

        bf16x8 af[4], bf[4];
        #pragma unroll
        for (int mi = 0; mi < 4; ++mi) {
            const int row = wm * 64 + mi * 16 + lo;
            const int slot = hi ^ ((row >> 1) & 3);
            af[mi] = *(const bf16x8*)&Abuf[row * 32 + slot * 8];
        }
        #pragma unroll
        for (int ni = 0; ni < 4; ++ni) {
            const int row = wn * 64 + ni * 16 + lo;
            const int slot = hi ^ ((row >> 1) & 3);
            bf[ni] = *(const bf16x8*)&Bbuf[row * 32 + slot * 8];
        }
        #pragma unroll
        for (int mi = 0; mi < 4; ++mi)
            #pragma unroll
            for (int ni = 0; ni < 4; ++ni)
                acc[mi][ni] = __builtin_amdgcn_mfma_f32_16x16x32_bf16(af[mi], bf[ni], acc[mi][ni], 0, 0, 0);
        __syncthreads();
    }

    if (EPI == 0) {
        unsigned short* __restrict__ Y = (unsigned short*)outp;
        #pragma unroll
        for (int mi = 0; mi < 4; ++mi) {
            #pragma unroll
            for (int r = 0; r < 4; ++r) {
                const int row = rowBase + wm * 64 + mi * 16 + hi * 4 + r;
                const int nn = row >> 11, tt = row & (T_ - 1);
                #pragma unroll
                for (int ni = 0; ni < 4; ++ni) {
                    const int col = colBase + wn * 64 + ni * 16 + lo;
                    const int hh = col >> 6, dd = col & 63;
                    Y[((size_t)((nn * H_ + hh) * T_ + tt)) * D_ + dd] = f2bf(acc[mi][ni][r] * oscale);
                }
            }
        }
    } else if (EPI == 1) {
        float* __restrict__ out = (float*)outp;
        float bias[4];
        #pragma unroll
        for (int ni = 0; ni < 4; ++ni) bias[ni] = bo[colBase + wn * 64 + ni * 16 + lo];
        #pragma unroll
        for (int mi = 0; mi < 4; ++mi) {
            #pragma unroll
            for (int r = 0; r < 4; ++r) {
                const int row = rowBase + wm * 64 + mi * 16 + hi * 4 + r;
                #pragma unroll
                for (int ni = 0; ni < 4; ++ni) {
                    const int col = colBase + wn * 64 + ni * 16 + lo;
                    out[(size_t)row * C_ + col] = acc[mi][ni][r] + bias[ni];
                }
            }
        }
    } else {   // EPI == 2: V^T  [ (nn*16+hh)*64 + dd ][ tt ]
        unsigned short* __restrict__ Y = (unsigned short*)outp;
        #pragma unroll
        for (int mi = 0; mi < 4; ++mi) {
            #pragma unroll
            for (int r = 0; r < 4; ++r) {
                const int row = rowBase + wm * 64 + mi * 16 + hi * 4 + r;
                const int nn = row >> 11, tt = row & (T_ - 1);
                #pragma unroll
                for (int ni = 0; ni < 4; ++ni) {
                    const int col = colBase + wn * 64 + ni * 16 + lo;
                    Y[(size_t)((nn * 16 + (col >> 6)) * 64 + (col & 63)) * T_ + tt] = f2bf(acc[mi][ni][r]);
                }
            }
        }
    }
}

// ---------------------------------------------------------------------------
// 32x32 MFMA flash attention (m214-style).
// Grid: 1024 blocks (16 qtiles x 64 heads, longest-first). Block = 4 waves;
// wave w owns q-rows [qb+32w, qb+32w+32). KV tile = 64 keys, double-buffered
// K ([k][64]) + V^T ([d][64k]) in LDS via global_load_lds, XOR-pre-swizzled
// source (16B granule ^ (row&7)).
// mfma_f32_32x32x16_bf16: A[l&31][(l>>5)*8+j], B[(l>>5)*8+j][l&31],
// C/D: col=l&31, row=(r&3)+8*(r>>2)+4*(l>>5)  (m74/m101-verified).
// Swapped QK^T: lane holds 32 scores of q-row (l&31); cross-half reductions
// via __shfl_xor(,32) (NOT permlane-swap on identical values — round-5 bug).
// P->PA frags via cvt_pk+permlane32_swap on distinct registers (T12).
// ---------------------------------------------------------------------------
__global__ __launch_bounds__(256, 2) void attn_mfma(const unsigned short* __restrict__ qg,
                                                    const unsigned short* __restrict__ kg,
                                                    const unsigned short* __restrict__ vtg,
                                                    unsigned short* __restrict__ ob) {
    __shared__ __align__(16) unsigned short Kt[2][64 * 64];
    __shared__ __align__(16) unsigned short Vt[2][64 * 64];

    const int tid  = threadIdx.x;
    const int w    = tid >> 6;
    const int lane = tid & 63;
    const int ql   = lane & 31;      // this lane's q-row (and d-col in PV)
    const int h    = lane >> 5;
    const int bid  = blockIdx.x;
    const int qtile = 15 - (bid >> 6);           // longest first
    const int nh   = bid & 63;
    const int qb   = qtile * 128;
    const size_t base  = (size_t)nh * (T_ * D_);
    const size_t vbase = (size_t)nh * 64 * T_;
    const int qrow0 = qb + w * 32;

    // Q B-fragments (held whole kernel); Q pre-scaled by log2e/sqrt(C).
    bf16x8 qf[4];
    #pragma unroll
    for (int dsl = 0; dsl < 4; ++dsl)
        qf[dsl] = *(const bf16x8*)(qg + base + (size_t)(qrow0 + ql) * D_ + dsl * 16 + h * 8);

    f32x16 acc0 = (f32x16)(0.f), acc1 = (f32x16)(0.f);
    float mrun = -INFINITY, lrun = 0.f;

    const int mynkt  = (qrow0 >> 6) + 1;
    const int nktmax = (qb >> 6) + 2;
    const int csubdiag = (w & 1) + 1;

    // staging constants: thread handles 16B chunks i0, i1 of each tile
    const int i0 = tid, i1 = tid + 256;
    const int kr0 = i0 >> 3, kc0 = ((i0 & 7) ^ (kr0 & 7)) * 8;
    const int kr1 = i1 >> 3, kc1 = ((i1 & 7) ^ (kr1 & 7)) * 8;

    #define STAGE(kt_, buf_)                                                            \
        do {                                                                            \
            const int kb_ = (kt_) * 64;                                                 \
            GLDS16(kg + base + (size_t)(kb_ + kr0) * D_ + kc0, &Kt[buf_][i0 * 8]);      \
            GLDS16(kg + base + (size_t)(kb_ + kr1) * D_ + kc1, &Kt[buf_][i1 * 8]);      \
            GLDS16(vtg + vbase + (size_t)kr0 * T_ + kb_ + kc0, &Vt[buf_][i0 * 8]);      \
            GLDS16(vtg + vbase + (size_t)kr1 * T_ + kb_ + kc1, &Vt[buf_][i1 * 8]);      \
        } while (0)

    STAGE(0, 0);
    __syncthreads();
    int cur = 0;

    for (int kt = 0; kt < nktmax; ++kt) {
        if (kt + 1 < nktmax) STAGE(kt + 1, cur ^ 1);

        if (kt < mynkt) {
            const bool diag = (kt == mynkt - 1);
            const int csub = diag ? csubdiag : 2;
            const unsigned short* Kb = Kt[cur];
            const unsigned short* Vb = Vt[cur];

            // ---- S^T = K * Q^T ----
            f32x16 s0, s1;
            __builtin_amdgcn_s_setprio(1);
            {
                f32x16 z = (f32x16)(0.f);
                #pragma unroll
                for (int dsl = 0; dsl < 4; ++dsl) {
                    const bf16x8 ka = *(const bf16x8*)&Kb[ql * 64 + ((dsl * 2 + h) ^ (ql & 7)) * 8];
                    z = __builtin_amdgcn_mfma_f32_32x32x16_bf16(ka, qf[dsl], z, 0, 0, 0);
                }
                s0 = z;
            }
            if (csub > 1) {
                f32x16 z = (f32x16)(0.f);
                #pragma unroll
                for (int dsl = 0; dsl < 4; ++dsl) {
                    const bf16x8 ka = *(const bf16x8*)&Kb[(32 + ql) * 64 + ((dsl * 2 + h) ^ (ql & 7)) * 8];
                    z = __builtin_amdgcn_mfma_f32_32x32x16_bf16(ka, qf[dsl], z, 0, 0, 0);
                }
                s1 = z;
            }
            __builtin_amdgcn_s_setprio(0);

            // ---- causal mask (diag tile: mask subtile csub-1 where k > q) ----
            if (diag) {
                #pragma unroll
                for (int r = 0; r < 16; ++r) {
                    const int rc = (r & 3) + 8 * (r >> 2) + 4 * h;
                    if (csub == 1) { if (rc > ql) s0[r] = -1e30f; }
                    else           { if (rc > ql) s1[r] = -1e30f; }
                }
            }

            // ---- row max: in-lane + cross-half shfl_xor ----
            float tm = -1e30f;
            #pragma unroll
            for (int r = 0; r < 16; ++r) tm = fmaxf(tm, s0[r]);
            if (csub > 1) {
                #pragma unroll
                for (int r = 0; r < 16; ++r) tm = fmaxf(tm, s1[r]);
            }
            tm = fmaxf(tm, __shfl_xor(tm, 32));

            // ---- defer-max rescale (T13, THR=8 in log2 domain) ----
            if (!__all(tm <= mrun + 8.f)) {
                const float mnew = fmaxf(mrun, tm);
                const float fsc = exp2f(mrun - mnew);
                mrun = mnew;
                lrun *= fsc;
                #pragma unroll
                for (int r = 0; r < 16; ++r) {
                    const float f = __shfl(fsc, (r & 3) + 8 * (r >> 2) + 4 * h);
                    acc0[r] *= f; acc1[r] *= f;
                }
            }

            // ---- P = exp2(S - m), row sum ----
            float psum = 0.f;
            #pragma unroll
            for (int r = 0; r < 16; ++r) { s0[r] = exp2f(s0[r] - mrun); psum += s0[r]; }
            if (csub > 1) {
                #pragma unroll
                for (int r = 0; r < 16; ++r) { s1[r] = exp2f(s1[r] - mrun); psum += s1[r]; }
            }
            psum += __shfl_xor(psum, 32);
            lrun += psum;

            // ---- PA fragments in-register (T12: cvt_pk + permlane32_swap) ----
            bf16x8 pa[4];
            #pragma unroll
            for (int a = 0; a < 2; ++a) {
                if (a < csub) {
                    #pragma unroll
                    for (int b = 0; b < 2; ++b) {
                        const f32x16& P = a ? s1 : s0;
                        unsigned w0 = cvtpk(P[8 * b + 0], P[8 * b + 1]);
                        unsigned w1 = cvtpk(P[8 * b + 2], P[8 * b + 3]);
                        unsigned w2 = cvtpk(P[8 * b + 4], P[8 * b + 5]);
                        unsigned w3 = cvtpk(P[8 * b + 6], P[8 * b + 7]);
                        PLSWAP(w0, w2);   // distinct registers: safe
                        PLSWAP(w1, w3);
                        unsigned wd[4] = {w0, w1, w2, w3};
                        pa[2 * a + b] = *(bf16x8*)wd;
                    }
                }
            }

            // ---- O += P V ----
            __builtin_amdgcn_s_setprio(1);
            #pragma unroll
            for (int ks = 0; ks < 4; ++ks) {
                if (ks < 2 * csub) {
                    const bf16x8 vf0 = *(const bf16x8*)&Vb[ql * 64 + ((ks * 2 + h) ^ (ql & 7)) * 8];
                    const bf16x8 vf1 = *(const bf16x8*)&Vb[(32 + ql) * 64 + ((ks * 2 + h) ^ (ql & 7)) * 8];
                    acc0 = __builtin_amdgcn_mfma_f32_32x32x16_bf16(pa[ks], vf0, acc0, 0, 0, 0);
                    acc1 = __builtin_amdgcn_mfma_f32_32x32x16_bf16(pa[ks], vf1, acc1, 0, 0, 0);
                }
            }
            __builtin_amdgcn_s_setprio(0);
        }
        __syncthreads();
        cur ^= 1;
    }

    // ---- epilogue: normalize, write bf16 [N*T, C] ----
    const float linv = 1.f / lrun;
    const int nn = nh >> 4, hh = nh & 15;
    #pragma unroll
    for (int r = 0; r < 16; ++r) {
        const int rc = (r & 3) + 8 * (r >> 2) + 4 * h;
        const float li = __shfl(linv, rc);
        const size_t rb = (size_t)(nn * T_ + qrow0 + rc) * C_ + hh * 64;
        ob[rb + ql]      = f2bf(acc0[r] * li);
        ob[rb + 32 + ql] = f2bf(acc1[r] * li);
    }
    #undef STAGE
}

// ---------------------------------------------------------------------------
extern "C" void kernel_launch(void* const* d_in, const int* in_sizes, int n_in,
                              void* d_out, int out_size, void* d_ws, size_t ws_size,
                              hipStream_t stream) {
    const float* x  = (const float*)d_in[0];
    const float* Wq = (const float*)d_in[1];
    const float* Wk = (const float*)d_in[2];
    const float* Wv = (const float*)d_in[3];
    const float* Wo = (const float*)d_in[4];
    const float* bo = (const float*)d_in[5];
    float* out = (float*)d_out;

    unsigned short* ws = (unsigned short*)d_ws;
    unsigned short* x_bf  = ws;
    unsigned short* w_bf  = x_bf + (size_t)NTC;
    unsigned short* q_bf  = w_bf + (size_t)4 * WELEM;
    unsigned short* k_bf  = q_bf + (size_t)NTC;
    unsigned short* vt_bf = k_bf + (size_t)NTC;
    unsigned short* a_bf  = vt_bf + (size_t)NTC;

    cast_x<<<NTC / (8 * 256), 256, 0, stream>>>(x, x_bf);
    dim3 gw(WELEM / (8 * 256), 4);
    cast_w4<<<gw, 256, 0, stream>>>(Wq, Wk, Wv, Wo, w_bf);

    dim3 gg(N_ * T_ / 128, C_ / 128);
    // Q pre-scaled by log2(e)/sqrt(C) so attention works in exp2 domain.
    gemm_bf16<0><<<gg, 256, 0, stream>>>(x_bf, w_bf + 0 * (size_t)WELEM, nullptr, q_bf, 0.03125f * 1.44269504f);
    gemm_bf16<0><<<gg, 256, 0, stream>>>(x_bf, w_bf + 1 * (size_t)WELEM, nullptr, k_bf, 1.0f);
    gemm_bf16<2><<<gg, 256, 0, stream>>>(x_bf, w_bf + 2 * (size_t)WELEM, nullptr, vt_bf, 1.0f);

    attn_mfma<<<(T_ / 128) * (N_ * H_), 256, 0, stream>>>(q_bf, k_bf, vt_bf, a_bf);

    gemm_bf16<1><<<gg, 256, 0, stream>>>(a_bf, w_bf + 3 * (size_t)WELEM, bo, out, 1.0f);
}